// Round 10
// baseline (453.701 us; speedup 1.0000x reference)
//
#include <hip/hip_runtime.h>
#include <stdint.h>

typedef __bf16 bf16;
typedef __attribute__((ext_vector_type(8))) bf16 bf16x8;
typedef __attribute__((ext_vector_type(4))) bf16 bf16x4;
typedef __attribute__((ext_vector_type(4))) float f32x4;

#define T_DIM 512
#define H_DIM 4096
#define F_DIM 14336

// Tile = 128 rows x 64 cols bf16 = 8192 elems = 16 KB, stored/consumed in
// XOR-swizzled order: elem = r*64 + (c ^ ((r&7)<<3)).
__device__ __forceinline__ int swz(int r, int c) {
    return r * 64 + (c ^ ((r & 7) << 3));
}

__device__ __forceinline__ int xcd_remap(int d, int chunk) {
    return (d & 7) * chunk + (d >> 3);
}

// async global->LDS, 16B per lane. Dest = wave-uniform base + lane*16 (HW);
// source is per-lane. Tracked by vmcnt.
__device__ __forceinline__ void dma16(const void* g, void* l) {
    __builtin_amdgcn_global_load_lds(
        (const __attribute__((address_space(1))) void*)g,
        (__attribute__((address_space(3))) void*)l, 16, 0, 0);
}

// Fused counted-wait + barrier (race-safe form validated round 7/9):
// single asm block, memory clobber, sched_barrier fences at call sites.
#define BARRIER_VM(N)                                                        \
    {                                                                        \
        __builtin_amdgcn_sched_barrier(0);                                   \
        asm volatile("s_waitcnt vmcnt(" #N ") lgkmcnt(0)\n\ts_barrier" ::: "memory"); \
        __builtin_amdgcn_sched_barrier(0);                                   \
    }

// ---------------------------------------------------------------------------
// x (f32 [512][4096]) -> xb tiled: [panel p=m>>7][ktile c>>6][swz(r,c) tile]
__global__ void cvt_x_kernel(const float* __restrict__ x, bf16* __restrict__ xbt) {
    int i = (blockIdx.x * 256 + threadIdx.x) * 4;
    int m = i >> 12;
    int c = i & 4095;
    float4 v = *(const float4*)(x + i);
    bf16x4 o = {(bf16)v.x, (bf16)v.y, (bf16)v.z, (bf16)v.w};
    int p = m >> 7, rm = m & 127, kt = c >> 6, kc = c & 63;
    *(bf16x4*)(xbt + (size_t)(p * 64 + kt) * 8192 + swz(rm, kc)) = o;
}

// ---------------------------------------------------------------------------
// Fused gate+up. Tile 128(M) x 32(N), BK=64, 256 thr (4 waves = 2M x 2N).
// A: DMA'd from pre-swizzled xbt (double-buffered As). Weights: reg-staged
// (dequant), TWO sets, dequant->Bs double-buffered. One counted-vmcnt barrier
// per K-step.
struct WSet { int4 q1[2], q3[2]; float4 s1, z1, s3, z3; };

__global__ __launch_bounds__(256, 3)
void gemm_gateup(const bf16* __restrict__ A,   // tiled xbt
                 const int* __restrict__ Wq1, const float* __restrict__ Sc1,
                 const float* __restrict__ Zr1,
                 const int* __restrict__ Wq3, const float* __restrict__ Sc3,
                 const float* __restrict__ Zr3,
                 bf16* __restrict__ inter) {   // tiled output (224 ktiles)
    constexpr int KD = H_DIM;
    constexpr int NT = KD / 64;                     // 64 (even, >=4)
    __shared__ __align__(16) bf16 As[2][128 * 64];  // 32 KB
    __shared__ __align__(16) bf16 Bs1[2][32 * 64];  //  8 KB
    __shared__ __align__(16) bf16 Bs3[2][32 * 64];  //  8 KB

    const int l    = xcd_remap(blockIdx.x, 224);
    const int bx   = l & 3;
    const int by   = l >> 2;
    const int tid  = threadIdx.x;
    const int lane = tid & 63;
    const int wid  = tid >> 6;
    const int wm   = wid >> 1, wn = wid & 1;
    const int lr   = lane & 15;
    const int lk   = (lane >> 4) * 8;
    const int m0   = bx * 128;
    const int n0   = by * 32;
    const int grp  = n0 >> 6;

    const int b_r = (tid >> 4) * 2;
    const int b_c = (tid & 15) * 4;

    const char*  atile = (const char*)A + (size_t)bx * 64 * 16384;
    const size_t dmaoff = (size_t)wid * 4096 + lane * 16;

    const int*   q1B = Wq1 + (size_t)(n0 + b_r) * KD + b_c;
    const int*   q3B = Wq3 + (size_t)(n0 + b_r) * KD + b_c;
    const float* s1B = Sc1 + (size_t)grp * KD + b_c;
    const float* z1B = Zr1 + (size_t)grp * KD + b_c;
    const float* s3B = Sc3 + (size_t)grp * KD + b_c;
    const float* z3B = Zr3 + (size_t)grp * KD + b_c;

    f32x4 acc1[4], acc3[4];
    const f32x4 zf = {0.f, 0.f, 0.f, 0.f};
#pragma unroll
    for (int i = 0; i < 4; i++) { acc1[i] = zf; acc3[i] = zf; }

    WSet sA, sB;

#define GU_DMA(TILE, nb)                                                      \
    {                                                                         \
        const char* _s = atile + (size_t)(TILE) * 16384 + dmaoff;             \
        char* _d = (char*)&As[nb][0] + wid * 4096;                            \
        _Pragma("unroll")                                                     \
        for (int j = 0; j < 4; j++) dma16(_s + j * 1024, _d + j * 1024);      \
    }

#define GU_STAGE(S, K0)                                                       \
    {                                                                         \
        _Pragma("unroll")                                                     \
        for (int i = 0; i < 2; i++) {                                         \
            S.q1[i] = *(const int4*)(q1B + (size_t)i * KD + (K0));            \
            S.q3[i] = *(const int4*)(q3B + (size_t)i * KD + (K0));            \
        }                                                                     \
        S.s1 = *(const float4*)(s1B + (K0));                                  \
        S.z1 = *(const float4*)(z1B + (K0));                                  \
        S.s3 = *(const float4*)(s3B + (K0));                                  \
        S.z3 = *(const float4*)(z3B + (K0));                                  \
    }

#define GU_WLDS(S, nb)                                                        \
    {                                                                         \
        float4 n1, n3;                                                        \
        n1.x = -S.z1.x * S.s1.x; n1.y = -S.z1.y * S.s1.y;                     \
        n1.z = -S.z1.z * S.s1.z; n1.w = -S.z1.w * S.s1.w;                     \
        n3.x = -S.z3.x * S.s3.x; n3.y = -S.z3.y * S.s3.y;                     \
        n3.z = -S.z3.z * S.s3.z; n3.w = -S.z3.w * S.s3.w;                     \
        _Pragma("unroll")                                                     \
        for (int i = 0; i < 2; i++) {                                         \
            bf16x4 v;                                                         \
            v[0] = (bf16)fmaf((float)S.q1[i].x, S.s1.x, n1.x);                \
            v[1] = (bf16)fmaf((float)S.q1[i].y, S.s1.y, n1.y);                \
            v[2] = (bf16)fmaf((float)S.q1[i].z, S.s1.z, n1.z);                \
            v[3] = (bf16)fmaf((float)S.q1[i].w, S.s1.w, n1.w);                \
            *(bf16x4*)&Bs1[nb][swz(b_r + i, b_c)] = v;                        \
            bf16x4 u;                                                         \
            u[0] = (bf16)fmaf((float)S.q3[i].x, S.s3.x, n3.x);                \
            u[1] = (bf16)fmaf((float)S.q3[i].y, S.s3.y, n3.y);                \
            u[2] = (bf16)fmaf((float)S.q3[i].z, S.s3.z, n3.z);                \
            u[3] = (bf16)fmaf((float)S.q3[i].w, S.s3.w, n3.w);                \
            *(bf16x4*)&Bs3[nb][swz(b_r + i, b_c)] = u;                        \
        }                                                                     \
    }

#define GU_MFMA(nb)                                                           \
    {                                                                         \
        _Pragma("unroll")                                                     \
        for (int kk = 0; kk < 2; kk++) {                                      \
            bf16x8 af[4], b1, b3;                                             \
            _Pragma("unroll")                                                 \
            for (int mi = 0; mi < 4; mi++)                                    \
                af[mi] = *(const bf16x8*)&As[nb][swz(wm * 64 + mi * 16 + lr, kk * 32 + lk)]; \
            b1 = *(const bf16x8*)&Bs1[nb][swz(wn * 16 + lr, kk * 32 + lk)];   \
            b3 = *(const bf16x8*)&Bs3[nb][swz(wn * 16 + lr, kk * 32 + lk)];   \
            _Pragma("unroll")                                                 \
            for (int mi = 0; mi < 4; mi++) {                                  \
                acc1[mi] = __builtin_amdgcn_mfma_f32_16x16x32_bf16(af[mi], b1, acc1[mi], 0, 0, 0); \
                acc3[mi] = __builtin_amdgcn_mfma_f32_16x16x32_bf16(af[mi], b3, acc3[mi], 0, 0, 0); \
            }                                                                 \
        }                                                                     \
    }

    // Prologue: W0->sA->Bs[0]; DMA tile0->As[0]; W1->sB, W2->sA in flight.
    GU_STAGE(sA, 0);
    GU_DMA(0, 0);
    GU_WLDS(sA, 0);            // compiler-counted vmcnt waits W0 only
    GU_STAGE(sB, 64);
    GU_STAGE(sA, 128);
    BARRIER_VM(16);            // W1(8)+W2(8) newest -> DMA(0) complete

    // Step t consumes LDS[t&1]; W(k) lives in set (k&1): even->sA, odd->sB.
    for (int t = 0; t < NT; t += 2) {
        // ---- even step t (cur=0) ----
        if (t + 1 < NT) GU_DMA(t + 1, 1);
        __builtin_amdgcn_sched_barrier(0);
        GU_MFMA(0);
        if (t + 1 < NT) {
            GU_WLDS(sB, 1);                      // W(t+1), odd
            if (t + 3 < NT) {
                GU_STAGE(sB, (t + 3) * 64);
                BARRIER_VM(8);                   // 8 newest = W(t+3) -> DMA done
            } else {
                BARRIER_VM(0);
            }
        }
        // ---- odd step t+1 (cur=1) ----
        const int u = t + 1;
        if (u < NT) {
            if (u + 1 < NT) GU_DMA(u + 1, 0);
            __builtin_amdgcn_sched_barrier(0);
            GU_MFMA(1);
            if (u + 1 < NT) {
                GU_WLDS(sA, 0);                  // W(u+1), even
                if (u + 3 < NT) {
                    GU_STAGE(sA, (u + 3) * 64);
                    BARRIER_VM(8);
                } else {
                    BARRIER_VM(0);
                }
            }
        }
    }
#undef GU_DMA
#undef GU_STAGE
#undef GU_WLDS
#undef GU_MFMA

    // Epilogue: silu(gate)*up -> inter in TILED layout (for down's DMA).
    const int orow = (lane >> 4) * 4;
    const int cg   = n0 + wn * 16 + lr;           // global col in F
    const int kt   = cg >> 6, kc = cg & 63;
    bf16* itile = inter + (size_t)(bx * 224 + kt) * 8192;
#pragma unroll
    for (int mi = 0; mi < 4; mi++) {
#pragma unroll
        for (int r = 0; r < 4; r++) {
            int rm = (wm * 64 + mi * 16 + orow + r) & 127;
            float g = acc1[mi][r];
            float u = acc3[mi][r];
            float s = g / (1.0f + __expf(-g));
            itile[swz(rm, kc)] = (bf16)(s * u);
        }
    }
}

// ---------------------------------------------------------------------------
// Down proj, split-K. A = tiled inter (224 ktiles/panel). Same pipeline,
// single weight (4 vmem/stage set).
struct WSetD { int4 q[2]; float4 s, z; };

template<int SPLITK>
__global__ __launch_bounds__(256, 4)
void gemm_down(const bf16* __restrict__ A,    // tiled inter
               const int* __restrict__ Wq,
               const float* __restrict__ Sc, const float* __restrict__ Zr,
               float* __restrict__ partials) {
    constexpr int KD = F_DIM;
    constexpr int KC = KD / SPLITK;
    constexpr int NT = KC / 64;                    // 56/112/224 (even, >=4)
    __shared__ __align__(16) bf16 As[2][128 * 64]; // 32 KB
    __shared__ __align__(16) bf16 Bs[2][32 * 64];  //  8 KB

    const int l    = xcd_remap(blockIdx.x, 64 * SPLITK);
    const int bx   = l & 3;
    const int by   = (l >> 2) & 127;
    const int bz   = l >> 9;
    const int tid  = threadIdx.x;
    const int lane = tid & 63;
    const int wid  = tid >> 6;
    const int wm   = wid >> 1, wn = wid & 1;
    const int lr   = lane & 15;
    const int lk   = (lane >> 4) * 8;
    const int m0   = bx * 128;
    const int n0   = by * 32;
    const int grp  = n0 >> 6;
    const int kt0  = bz * (KC / 64);               // first ktile of this chunk

    const int b_r = (tid >> 4) * 2;
    const int b_c = (tid & 15) * 4;

    const char*  atile = (const char*)A + (size_t)(bx * 224 + kt0) * 16384;
    const size_t dmaoff = (size_t)wid * 4096 + lane * 16;
    const int    kbeg  = bz * KC;

    const int*   qB = Wq + (size_t)(n0 + b_r) * KD + kbeg + b_c;
    const float* sB_ = Sc + (size_t)grp * KD + kbeg + b_c;
    const float* zB_ = Zr + (size_t)grp * KD + kbeg + b_c;

    f32x4 acc[4];
    const f32x4 zf = {0.f, 0.f, 0.f, 0.f};
#pragma unroll
    for (int i = 0; i < 4; i++) acc[i] = zf;

    WSetD sA, sB;

#define GD_DMA(TILE, nb)                                                      \
    {                                                                         \
        const char* _s = atile + (size_t)(TILE) * 16384 + dmaoff;             \
        char* _d = (char*)&As[nb][0] + wid * 4096;                            \
        _Pragma("unroll")                                                     \
        for (int j = 0; j < 4; j++) dma16(_s + j * 1024, _d + j * 1024);      \
    }

#define GD_STAGE(S, K0)                                                       \
    {                                                                         \
        _Pragma("unroll")                                                     \
        for (int i = 0; i < 2; i++)                                           \
            S.q[i] = *(const int4*)(qB + (size_t)i * KD + (K0));              \
        S.s = *(const float4*)(sB_ + (K0));                                   \
        S.z = *(const float4*)(zB_ + (K0));                                   \
    }

#define GD_WLDS(S, nb)                                                        \
    {                                                                         \
        float4 nz;                                                            \
        nz.x = -S.z.x * S.s.x; nz.y = -S.z.y * S.s.y;                         \
        nz.z = -S.z.z * S.s.z; nz.w = -S.z.w * S.s.w;                         \
        _Pragma("unroll")                                                     \
        for (int i = 0; i < 2; i++) {                                         \
            bf16x4 v;                                                         \
            v[0] = (bf16)fmaf((float)S.q[i].x, S.s.x, nz.x);                  \
            v[1] = (bf16)fmaf((float)S.q[i].y, S.s.y, nz.y);                  \
            v[2] = (bf16)fmaf((float)S.q[i].z, S.s.z, nz.z);                  \
            v[3] = (bf16)fmaf((float)S.q[i].w, S.s.w, nz.w);                  \
            *(bf16x4*)&Bs[nb][swz(b_r + i, b_c)] = v;                         \
        }                                                                     \
    }

#define GD_MFMA(nb)                                                           \
    {                                                                         \
        _Pragma("unroll")                                                     \
        for (int kk = 0; kk < 2; kk++) {                                      \
            bf16x8 af[4], bfr;                                                \
            _Pragma("unroll")                                                 \
            for (int mi = 0; mi < 4; mi++)                                    \
                af[mi] = *(const bf16x8*)&As[nb][swz(wm * 64 + mi * 16 + lr, kk * 32 + lk)]; \
            bfr = *(const bf16x8*)&Bs[nb][swz(wn * 16 + lr, kk * 32 + lk)];   \
            _Pragma("unroll")                                                 \
            for (int mi = 0; mi < 4; mi++)                                    \
                acc[mi] = __builtin_amdgcn_mfma_f32_16x16x32_bf16(af[mi], bfr, acc[mi], 0, 0, 0); \
        }                                                                     \
    }

    GD_STAGE(sA, 0);
    GD_DMA(0, 0);
    GD_WLDS(sA, 0);
    GD_STAGE(sB, 64);
    GD_STAGE(sA, 128);
    BARRIER_VM(8);             // W1(4)+W2(4) newest -> DMA(0) complete

    for (int t = 0; t < NT; t += 2) {
        if (t + 1 < NT) GD_DMA(t + 1, 1);
        __builtin_amdgcn_sched_barrier(0);
        GD_MFMA(0);
        if (t + 1 < NT) {
            GD_WLDS(sB, 1);
            if (t + 3 < NT) {
                GD_STAGE(sB, (t + 3) * 64);
                BARRIER_VM(4);
            } else {
                BARRIER_VM(0);
            }
        }
        const int u = t + 1;
        if (u < NT) {
            if (u + 1 < NT) GD_DMA(u + 1, 0);
            __builtin_amdgcn_sched_barrier(0);
            GD_MFMA(1);
            if (u + 1 < NT) {
                GD_WLDS(sA, 0);
                if (u + 3 < NT) {
                    GD_STAGE(sA, (u + 3) * 64);
                    BARRIER_VM(4);
                } else {
                    BARRIER_VM(0);
                }
            }
        }
    }
#undef GD_DMA
#undef GD_STAGE
#undef GD_WLDS
#undef GD_MFMA

    float* po = partials + (size_t)bz * T_DIM * H_DIM;
    const int orow = (lane >> 4) * 4;
#pragma unroll
    for (int mi = 0; mi < 4; mi++) {
#pragma unroll
        for (int r = 0; r < 4; r++) {
            int m = m0 + wm * 64 + mi * 16 + orow + r;
            int c = n0 + wn * 16 + lr;
            po[(size_t)m * H_DIM + c] = acc[mi][r];
        }
    }
}

// ---------------------------------------------------------------------------
template<int S>
__global__ void reduce_kernel(const float* __restrict__ partials, float* __restrict__ out) {
    size_t i = ((size_t)blockIdx.x * 256 + threadIdx.x) * 4;
    f32x4 a = *(const f32x4*)(partials + i);
#pragma unroll
    for (int s = 1; s < S; s++)
        a += *(const f32x4*)(partials + (size_t)s * T_DIM * H_DIM + i);
    *(f32x4*)(out + i) = a;
}

// ---------------------------------------------------------------------------
extern "C" void kernel_launch(void* const* d_in, const int* in_sizes, int n_in,
                              void* d_out, int out_size, void* d_ws, size_t ws_size,
                              hipStream_t stream) {
    const float* x   = (const float*)d_in[0];
    const int*   w1q = (const int*)d_in[1];
    const float* w1s = (const float*)d_in[2];
    const float* w1z = (const float*)d_in[3];
    const int*   w2q = (const int*)d_in[4];
    const float* w2s = (const float*)d_in[5];
    const float* w2z = (const float*)d_in[6];
    const int*   w3q = (const int*)d_in[7];
    const float* w3s = (const float*)d_in[8];
    const float* w3z = (const float*)d_in[9];

    bf16*  xb    = (bf16*)d_ws;                         // tiled [4][64][8192]
    bf16*  inter = xb + (size_t)T_DIM * H_DIM;          // tiled [4][224][8192]
    float* parts = (float*)(inter + (size_t)T_DIM * F_DIM);

    const size_t base   = (size_t)T_DIM * H_DIM * 2 + (size_t)T_DIM * F_DIM * 2;
    const size_t pbytes = (size_t)T_DIM * H_DIM * 4;

    cvt_x_kernel<<<dim3(2048), dim3(256), 0, stream>>>(x, xb);

    gemm_gateup<<<dim3(1792), dim3(256), 0, stream>>>(
        xb, w1q, w1s, w1z, w3q, w3s, w3z, inter);

    if (ws_size >= base + 4 * pbytes) {
        gemm_down<4><<<dim3(2048), dim3(256), 0, stream>>>(inter, w2q, w2s, w2z, parts);
        reduce_kernel<4><<<dim3(2048), dim3(256), 0, stream>>>(parts, (float*)d_out);
    } else if (ws_size >= base + 2 * pbytes) {
        gemm_down<2><<<dim3(1024), dim3(256), 0, stream>>>(inter, w2q, w2s, w2z, parts);
        reduce_kernel<2><<<dim3(2048), dim3(256), 0, stream>>>(parts, (float*)d_out);
    } else {
        gemm_down<1><<<dim3(512), dim3(256), 0, stream>>>(inter, w2q, w2s, w2z, parts);
        reduce_kernel<1><<<dim3(2048), dim3(256), 0, stream>>>(parts, (float*)d_out);
    }
}